// Round 1
// baseline (345.033 us; speedup 1.0000x reference)
//
#include <hip/hip_runtime.h>
#include <math.h>
#include <stdint.h>

// ---------------- problem constants ----------------
#define NCHW    64                 // BS*CHS = 32*2
#define TLEN    131072             // samples per channel
#define IRLEN   32768
#define NTAPS   511
#define NBANDS  12
#define NOISELEN (IRLEN + NTAPS - 1)   // 33278

// ---------------- scan chunking ----------------
// Chunked envelope scan: C=256 output samples per worker, W=4096 warmup.
// Contraction of the one-pole follower makes warmup-from-0 converge to the
// exact trajectory (init 0 is an upper bound since gain_db <= 0; converges
// at ~attack rate). Chunks whose warmup reaches t<=0 are EXACT (zero pad
// keeps p=0 until t=0, matching the reference's zero init).
#define WUP     4096
#define CHK     256
#define NCHUNK  (TLEN / CHK)       // 512 (must be pow2: we use >>9, &511)
#define SP      (TLEN + WUP)       // padded per-channel stride of gain buffer

#define K10     0.16609640474436813f   // log2(10)/20   : 10^(z/20) = exp2(z*K10)
#define DB2     6.0205999132796239f    // 20*log10(2)   : 20*log10(a) = DB2*log2(a)

// tanh via exp2 (branch-free): tanh(z) = sign(z)*(1 - 2/(e^{2|z|}+1))
__device__ __forceinline__ float fast_tanh(float z) {
    float az = fabsf(z);
    float e  = exp2f(az * 2.8853900817779268f);  // e^{2|z|}
    float r  = 1.0f - 2.0f / (e + 1.0f);
    return copysignf(r, z);
}

// soft-knee gain computer: returns desired gain reduction in dB (<= 0)
__device__ __forceinline__ float gain_db_one(float xs, float g, float thr,
                                             float q, float knee, float inv2k) {
    float y    = fast_tanh(xs * g);
    float a    = fabsf(y) + 1e-8f;
    float xdb  = __log2f(a) * DB2;
    float over = xdb - thr;
    float h    = over + 0.5f * knee;
    float gk   = q * h * h * inv2k;              // knee region: g - xdb
    float t2   = 2.0f * over;
    return (t2 < -knee) ? 0.0f : ((t2 > knee) ? q * over : gk);
}

// ---------------- K1: distortion + gain computer -> padded gain curve ------
__global__ __launch_bounds__(256) void k1_gain(
    const float* __restrict__ x,
    const float* __restrict__ p_drive, const float* __restrict__ p_thr,
    const float* __restrict__ p_ratio, const float* __restrict__ p_knee,
    const float* __restrict__ band_gains,
    float* __restrict__ cur, int* __restrict__ flag)
{
    if (blockIdx.x == 0 && blockIdx.y == 0 && threadIdx.x == 0) {
        int f = 0;
        #pragma unroll
        for (int b = 0; b < NBANDS; ++b) f |= (band_gains[b] != 0.0f) ? 1 : 0;
        *flag = f;   // reverb wet path needed at all?
    }
    int ch   = blockIdx.y;
    int off4 = (blockIdx.x * 256 + threadIdx.x) * 4;
    if (off4 >= SP) return;
    float4* dst = (float4*)(cur + (size_t)ch * SP + off4);
    if (off4 < WUP) {                       // leading zero pad per channel
        *dst = make_float4(0.f, 0.f, 0.f, 0.f);
        return;
    }
    int t = off4 - WUP;
    const float4 xv = *(const float4*)(x + (size_t)ch * TLEN + t);

    float g     = exp2f(p_drive[0] * K10);          // 10^(drive/20)
    float thr   = p_thr[0];
    float ratio = p_ratio[0];
    float knee  = fmaxf(p_knee[0], 1e-3f);
    float q     = 1.0f / ratio - 1.0f;
    float inv2k = 1.0f / (2.0f * knee);

    float4 o;
    o.x = gain_db_one(xv.x, g, thr, q, knee, inv2k);
    o.y = gain_db_one(xv.y, g, thr, q, knee, inv2k);
    o.z = gain_db_one(xv.z, g, thr, q, knee, inv2k);
    o.w = gain_db_one(xv.w, g, thr, q, knee, inv2k);
    *dst = o;
}

// ---------------- K2: chunked one-pole attack/release envelope ------------
__device__ __forceinline__ float env_step(float p, float c, float aa, float ar) {
    float d  = p - c;
    float na = fmaf(aa, d, c);   // attack candidate
    float nr = fmaf(ar, d, c);   // release candidate
    return (c < p) ? na : nr;    // attack when reduction grows (cur < prev)
}

__device__ __forceinline__ void load_tile(float4 (&buf)[16], const float4* s4, int tile) {
    const float4* p = s4 + tile * 16;
    #pragma unroll
    for (int u = 0; u < 16; ++u) buf[u] = p[u];
}

__device__ __forceinline__ void comp_tile(float4 (&buf)[16], float& p,
                                          float aa, float ar,
                                          float4* d4, bool emit) {
    #pragma unroll
    for (int u = 0; u < 16; ++u) {
        float4 c = buf[u];
        float4 o;
        o.x = p = env_step(p, c.x, aa, ar);
        o.y = p = env_step(p, c.y, aa, ar);
        o.z = p = env_step(p, c.z, aa, ar);
        o.w = p = env_step(p, c.w, aa, ar);
        if (emit) d4[u] = o;
    }
}

__global__ __launch_bounds__(256, 1) void k2_env(
    const float* __restrict__ cur,
    const float* __restrict__ p_atk, const float* __restrict__ p_rel,
    float* __restrict__ smooth)
{
    int w  = blockIdx.x * 256 + threadIdx.x;   // worker = (channel, chunk)
    int ch = w >> 9;                           // / NCHUNK (512)
    int j  = w & (NCHUNK - 1);

    // start position t = j*CHK - WUP  ->  padded index ch*SP + j*CHK
    const float4* s4 = (const float4*)(cur + (size_t)ch * SP + (size_t)j * CHK);
    float* dst = smooth + (size_t)ch * TLEN + (size_t)j * CHK;

    float aa = expf(-1.0f / (48000.0f * p_atk[0] * 0.001f));
    float ar = expf(-1.0f / (48000.0f * p_rel[0] * 0.001f));

    const int nt = (WUP + CHK) / 64;   // 68 tiles of 64 samples
    const int ot = WUP / 64;           // first emitting tile (uniform!)
    float4* d4base = (float4*)dst - ot * 16;

    float4 A[16], B[16];
    float p = 0.0f;
    load_tile(A, s4, 0);
    for (int t0 = 0; t0 < nt; t0 += 2) {
        load_tile(B, s4, t0 + 1);                       // prefetch next tile
        comp_tile(A, p, aa, ar, d4base + t0 * 16, t0 >= ot);
        if (t0 + 2 < nt) load_tile(A, s4, t0 + 2);      // prefetch next+1
        comp_tile(B, p, aa, ar, d4base + (t0 + 1) * 16, t0 + 1 >= ot);
    }
}

// ---------------- K3: apply smoothed gain + dry mix -----------------------
__global__ __launch_bounds__(256) void k3_out(
    const float* __restrict__ x, const float* __restrict__ smooth,
    const float* __restrict__ p_drive, const float* __restrict__ p_makeup,
    const float* __restrict__ p_mix, const int* __restrict__ flag,
    float* __restrict__ out, float* __restrict__ comp)
{
    int i4 = (blockIdx.x * 256 + threadIdx.x) * 4;
    float g   = exp2f(p_drive[0] * K10);
    float mk  = p_makeup[0];
    float mix = p_mix[0];
    float dry = 1.0f - mix;
    int f = *flag;

    float4 xv = *(const float4*)(x + i4);
    float4 sv = *(const float4*)(smooth + i4);
    float4 cv;
    cv.x = fast_tanh(xv.x * g) * exp2f((sv.x + mk) * K10);
    cv.y = fast_tanh(xv.y * g) * exp2f((sv.y + mk) * K10);
    cv.z = fast_tanh(xv.z * g) * exp2f((sv.z + mk) * K10);
    cv.w = fast_tanh(xv.w * g) * exp2f((sv.w + mk) * K10);

    float4 ov;
    ov.x = dry * cv.x; ov.y = dry * cv.y; ov.z = dry * cv.z; ov.w = dry * cv.w;
    *(float4*)(out + i4) = ov;
    if (f) *(float4*)(comp + i4) = cv;   // only needed by the wet fallback
}

// ---------------- K4 (guarded fallback): synthesize reverb IR -------------
__global__ __launch_bounds__(256) void k4_ir(
    const float* __restrict__ noise, const float* __restrict__ fir,
    const float* __restrict__ gains, const float* __restrict__ decays,
    const int* __restrict__ flag, float* __restrict__ ir)
{
    if (!*flag) return;   // band_gains all zero -> ir == 0, wet == 0
    __shared__ float sf[NBANDS * NTAPS];
    for (int i = threadIdx.x; i < NBANDS * NTAPS; i += 256) sf[i] = fir[i];
    __syncthreads();
    size_t total  = (size_t)NCHW * IRLEN;
    size_t stride = (size_t)gridDim.x * 256;
    for (size_t idx = blockIdx.x * 256 + threadIdx.x; idx < total; idx += stride) {
        int nch = (int)(idx >> 15);          // / IRLEN
        int n   = (int)(idx & (IRLEN - 1));
        float tl  = n * (1.0f / (IRLEN - 1));
        float acc = 0.0f;
        for (int b = 0; b < NBANDS; ++b) {
            float gb = gains[b];
            if (gb == 0.0f) continue;
            float env = expf(-(decays[b] * 10.0f + 1.0f) * tl) * gb;
            const float* np_ = noise + ((size_t)nch * NBANDS + b) * NOISELEN + n;
            const float* fb  = sf + b * NTAPS;
            float s = 0.0f;
            for (int k = 0; k < NTAPS; ++k) s = fmaf(np_[k], fb[k], s);
            acc = fmaf(env, s, acc);
        }
        ir[idx] = acc * (1.0f / NBANDS);
    }
}

// ---------------- K5 (guarded fallback): wet convolution + mix ------------
__global__ __launch_bounds__(256) void k5_wet(
    const float* __restrict__ comp, const float* __restrict__ ir,
    const float* __restrict__ p_mix, const int* __restrict__ flag,
    float* __restrict__ out)
{
    if (!*flag) return;
    float mix = p_mix[0];
    size_t total  = (size_t)NCHW * TLEN;
    size_t stride = (size_t)gridDim.x * 256;
    for (size_t idx = blockIdx.x * 256 + threadIdx.x; idx < total; idx += stride) {
        int nch = (int)(idx >> 17);          // / TLEN
        int t   = (int)(idx & (TLEN - 1));
        const float* c   = comp + (size_t)nch * TLEN;
        const float* irp = ir + (size_t)nch * IRLEN;
        int kmax = (t < IRLEN - 1) ? t : (IRLEN - 1);
        float s = 0.0f;
        for (int k = 0; k <= kmax; ++k) s = fmaf(irp[k], c[t - k], s);
        out[idx] += mix * s;
    }
}

// ---------------- host-side launch ----------------------------------------
extern "C" void kernel_launch(void* const* d_in, const int* in_sizes, int n_in,
                              void* d_out, int out_size, void* d_ws, size_t ws_size,
                              hipStream_t stream)
{
    const float* x      = (const float*)d_in[0];
    const float* drive  = (const float*)d_in[1];
    const float* thr    = (const float*)d_in[2];
    const float* ratio  = (const float*)d_in[3];
    const float* atk    = (const float*)d_in[4];
    const float* rel    = (const float*)d_in[5];
    const float* knee   = (const float*)d_in[6];
    const float* makeup = (const float*)d_in[7];
    const float* mix    = (const float*)d_in[8];
    const float* bg     = (const float*)d_in[9];
    const float* bd     = (const float*)d_in[10];
    const float* noise  = (const float*)d_in[11];
    const float* fir    = (const float*)d_in[12];
    float* out = (float*)d_out;

    // workspace layout (all 16B aligned):
    // [flag:16B][cur: NCHW*SP f32 (34.6MB)][smooth: NCHW*TLEN f32 (33.6MB)]
    // [ir: NCHW*IRLEN f32 (8.4MB)]   ; comp (fallback only) reuses cur
    char*  w      = (char*)d_ws;
    int*   flag   = (int*)w;
    float* cur    = (float*)(w + 16);
    float* smooth = cur + (size_t)NCHW * SP;
    float* ir     = smooth + (size_t)NCHW * TLEN;
    float* comp   = cur;   // cur is dead after k2

    k1_gain<<<dim3(SP / 1024, NCHW), 256, 0, stream>>>(x, drive, thr, ratio, knee, bg, cur, flag);
    k2_env<<<(NCHW * NCHUNK) / 256, 256, 0, stream>>>(cur, atk, rel, smooth);
    k3_out<<<(NCHW * TLEN / 4) / 256, 256, 0, stream>>>(x, smooth, drive, makeup, mix, flag, out, comp);
    k4_ir<<<2048, 256, 0, stream>>>(noise, fir, bg, bd, flag, ir);
    k5_wet<<<2048, 256, 0, stream>>>(comp, ir, mix, flag, out);
}

// Round 2
// 285.857 us; speedup vs baseline: 1.2070x; 1.2070x over previous
//
#include <hip/hip_runtime.h>
#include <math.h>
#include <stdint.h>

// ---------------- problem constants ----------------
#define NCHW    64                 // BS*CHS = 32*2 channels (= wave width!)
#define TLEN    131072             // samples per channel
#define IRLEN   32768
#define NTAPS   511
#define NBANDS  12
#define NOISELEN (IRLEN + NTAPS - 1)   // 33278

// ---------------- scan chunking ----------------
// One wave per chunk, lane = channel. Warmup-from-0 converges to the exact
// trajectory (contraction); chunks whose warmup reaches t<=0 are EXACT.
#define WUP     4096
#define CHK     256
#define NCHUNK  (TLEN / CHK)       // 512

#define K10     0.16609640474436813f   // log2(10)/20
#define DB2     6.0205999132796239f    // 20*log10(2)

// tanh via exp2: tanh(z) = sign(z)*(1 - 2/(e^{2|z|}+1))
__device__ __forceinline__ float fast_tanh(float z) {
    float az = fabsf(z);
    float e  = exp2f(az * 2.8853900817779268f);
    float r  = 1.0f - 2.0f / (e + 1.0f);
    return copysignf(r, z);
}

__device__ __forceinline__ float gain_db_one(float xs, float g, float thr,
                                             float q, float knee, float inv2k) {
    float y    = fast_tanh(xs * g);
    float a    = fabsf(y) + 1e-8f;
    float xdb  = __log2f(a) * DB2;
    float over = xdb - thr;
    float h    = over + 0.5f * knee;
    float gk   = q * h * h * inv2k;
    float t2   = 2.0f * over;
    return (t2 < -knee) ? 0.0f : ((t2 > knee) ? q * over : gk);
}

// ---------- K1: gain computer -> transposed packed layout -----------------
// acur2 flat layout: addr(t, ch) = (t/2)*128 + ch*2 + (t&1)   [floats]
// stores ka = (1-alpha_a) * gain_db   (attack-branch additive constant)
__global__ __launch_bounds__(256) void k1_gain(
    const float* __restrict__ x,
    const float* __restrict__ p_drive, const float* __restrict__ p_thr,
    const float* __restrict__ p_ratio, const float* __restrict__ p_knee,
    const float* __restrict__ p_atk,   const float* __restrict__ band_gains,
    float* __restrict__ acur2, int* __restrict__ flag)
{
    if (blockIdx.x == 0 && threadIdx.x == 0) {
        int f = 0;
        #pragma unroll
        for (int b = 0; b < NBANDS; ++b) f |= (band_gains[b] != 0.0f) ? 1 : 0;
        *flag = f;
    }
    __shared__ float S[64 * 65];           // S[sample][ch], pitch 65
    int t0 = blockIdx.x * 64;
    int l  = threadIdx.x & 63;             // sample within tile
    int w  = threadIdx.x >> 6;             // 0..3 -> 16 channels each

    float g     = exp2f(p_drive[0] * K10);
    float thr   = p_thr[0];
    float knee  = fmaxf(p_knee[0], 1e-3f);
    float q     = 1.0f / p_ratio[0] - 1.0f;
    float inv2k = 1.0f / (2.0f * knee);
    float aa    = expf(-1.0f / (48.0f * p_atk[0]));
    float omaa  = 1.0f - aa;

    #pragma unroll
    for (int i = 0; i < 16; ++i) {
        int ch = w * 16 + i;
        float xv = x[(size_t)ch * TLEN + t0 + l];     // coalesced 256B/wave
        S[l * 65 + ch] = omaa * gain_db_one(xv, g, thr, q, knee, inv2k);
    }
    __syncthreads();

    float4* dst = (float4*)(acur2 + (size_t)t0 * 64);  // tile base
    #pragma unroll
    for (int i = 0; i < 4; ++i) {
        int gq = threadIdx.x + 256 * i;   // float4 index within tile, 0..1023
        int s2 = gq >> 5;                 // packed row (2 samples)
        int cp = (gq & 31) * 2;           // channel pair base
        float4 v;
        v.x = S[(2 * s2)     * 65 + cp];
        v.y = S[(2 * s2 + 1) * 65 + cp];
        v.z = S[(2 * s2)     * 65 + cp + 1];
        v.w = S[(2 * s2 + 1) * 65 + cp + 1];
        dst[gq] = v;                      // coalesced 1KB/wave
    }
}

// ---------- K2: chunked envelope scan, lane = channel ---------------------
__device__ __forceinline__ void k2_load(float2 (&buf)[32], const float2* s2, int th) {
    #pragma unroll
    for (int u = 0; u < 32; ++u) buf[u] = s2[(th + u) * 64];
}

__device__ __forceinline__ void k2_comp(float2 (&buf)[32], float& p,
                                        float aa, float ar, float rho,
                                        float2* d2, int th, bool emit) {
    #pragma unroll
    for (int u = 0; u < 32; ++u) {
        float2 a = buf[u];
        float fa = fmaf(aa, p, a.x);
        float fr = fmaf(ar, p, rho * a.x);   // kr = rho*ka, off critical chain
        p = fminf(fa, fr);                    // min picks attack iff c < p
        float2 o; o.x = p;
        fa = fmaf(aa, p, a.y);
        fr = fmaf(ar, p, rho * a.y);
        p = fminf(fa, fr);
        o.y = p;
        if (emit) d2[(th + u) * 64] = o;      // coalesced 512B/wave
    }
}

__global__ __launch_bounds__(64) void k2_env(
    const float* __restrict__ acur2,
    const float* __restrict__ p_atk, const float* __restrict__ p_rel,
    float* __restrict__ smooth2)
{
    int b    = blockIdx.x;
    int j    = ((b & 7) << 6) | (b >> 3);   // XCD-contiguous chunk ranges
    int lane = threadIdx.x;

    float aa  = expf(-1.0f / (48.0f * p_atk[0]));
    float ar  = expf(-1.0f / (48.0f * p_rel[0]));
    float rho = (1.0f - ar) / (1.0f - aa);

    int t0   = (j >= WUP / CHK) ? (j * CHK - WUP) : 0;   // exact for j<16
    int te   = j * CHK;
    int tend = te + CHK;
    int th0  = t0 >> 1, the = te >> 1, thend = tend >> 1;

    const float2* s2 = (const float2*)acur2 + lane;
    float2*       d2 = (float2*)smooth2 + lane;

    float p = 0.0f;
    float2 A[32], B[32];
    k2_load(A, s2, th0);
    for (int th = th0; th < thend; th += 64) {           // 2 tiles/iter
        k2_load(B, s2, th + 32);
        k2_comp(A, p, aa, ar, rho, d2, th, th >= the);
        if (th + 64 < thend) k2_load(A, s2, th + 64);
        k2_comp(B, p, aa, ar, rho, d2, th + 32, th + 32 >= the);
    }
}

// ---------- K3: transpose back + apply gain + dry mix ---------------------
__global__ __launch_bounds__(256) void k3_out(
    const float* __restrict__ x, const float* __restrict__ smooth2,
    const float* __restrict__ p_drive, const float* __restrict__ p_makeup,
    const float* __restrict__ p_mix, const int* __restrict__ flag,
    float* __restrict__ out, float* __restrict__ comp)
{
    __shared__ float S[32 * 130];          // packed rows, pitch 130 (+2 pad)
    int t0 = blockIdx.x * 64;

    const float4* src = (const float4*)(smooth2 + (size_t)t0 * 64);
    #pragma unroll
    for (int i = 0; i < 4; ++i) {
        int f4 = threadIdx.x + 256 * i;    // 0..1023
        float4 v = src[f4];                // coalesced 1KB/wave
        int f   = f4 * 4;
        float* d = S + (f >> 7) * 130 + (f & 127);
        d[0] = v.x; d[1] = v.y; d[2] = v.z; d[3] = v.w;
    }
    __syncthreads();

    int l = threadIdx.x & 63, w = threadIdx.x >> 6;
    float g   = exp2f(p_drive[0] * K10);
    float mk  = p_makeup[0];
    float mix = p_mix[0];
    float dry = 1.0f - mix;
    int f = *flag;

    #pragma unroll
    for (int i = 0; i < 16; ++i) {
        int ch = w * 16 + i;
        float sm = S[(l >> 1) * 130 + ch * 2 + (l & 1)];
        size_t idx = (size_t)ch * TLEN + t0 + l;
        float cv = fast_tanh(x[idx] * g) * exp2f((sm + mk) * K10);
        out[idx] = dry * cv;               // coalesced 256B/wave
        if (f) comp[idx] = cv;
    }
}

// ---------- K4 (guarded fallback): synthesize reverb IR -------------------
__global__ __launch_bounds__(256) void k4_ir(
    const float* __restrict__ noise, const float* __restrict__ fir,
    const float* __restrict__ gains, const float* __restrict__ decays,
    const int* __restrict__ flag, float* __restrict__ ir)
{
    if (!*flag) return;
    __shared__ float sf[NBANDS * NTAPS];
    for (int i = threadIdx.x; i < NBANDS * NTAPS; i += 256) sf[i] = fir[i];
    __syncthreads();
    size_t total  = (size_t)NCHW * IRLEN;
    size_t stride = (size_t)gridDim.x * 256;
    for (size_t idx = blockIdx.x * 256 + threadIdx.x; idx < total; idx += stride) {
        int nch = (int)(idx >> 15);
        int n   = (int)(idx & (IRLEN - 1));
        float tl  = n * (1.0f / (IRLEN - 1));
        float acc = 0.0f;
        for (int b = 0; b < NBANDS; ++b) {
            float gb = gains[b];
            if (gb == 0.0f) continue;
            float env = expf(-(decays[b] * 10.0f + 1.0f) * tl) * gb;
            const float* np_ = noise + ((size_t)nch * NBANDS + b) * NOISELEN + n;
            const float* fb  = sf + b * NTAPS;
            float s = 0.0f;
            for (int k = 0; k < NTAPS; ++k) s = fmaf(np_[k], fb[k], s);
            acc = fmaf(env, s, acc);
        }
        ir[idx] = acc * (1.0f / NBANDS);
    }
}

// ---------- K5 (guarded fallback): wet convolution + mix ------------------
__global__ __launch_bounds__(256) void k5_wet(
    const float* __restrict__ comp, const float* __restrict__ ir,
    const float* __restrict__ p_mix, const int* __restrict__ flag,
    float* __restrict__ out)
{
    if (!*flag) return;
    float mix = p_mix[0];
    size_t total  = (size_t)NCHW * TLEN;
    size_t stride = (size_t)gridDim.x * 256;
    for (size_t idx = blockIdx.x * 256 + threadIdx.x; idx < total; idx += stride) {
        int nch = (int)(idx >> 17);
        int t   = (int)(idx & (TLEN - 1));
        const float* c   = comp + (size_t)nch * TLEN;
        const float* irp = ir + (size_t)nch * IRLEN;
        int kmax = (t < IRLEN - 1) ? t : (IRLEN - 1);
        float s = 0.0f;
        for (int k = 0; k <= kmax; ++k) s = fmaf(irp[k], c[t - k], s);
        out[idx] += mix * s;
    }
}

// ---------- host-side launch ----------------------------------------------
extern "C" void kernel_launch(void* const* d_in, const int* in_sizes, int n_in,
                              void* d_out, int out_size, void* d_ws, size_t ws_size,
                              hipStream_t stream)
{
    const float* x      = (const float*)d_in[0];
    const float* drive  = (const float*)d_in[1];
    const float* thr    = (const float*)d_in[2];
    const float* ratio  = (const float*)d_in[3];
    const float* atk    = (const float*)d_in[4];
    const float* rel    = (const float*)d_in[5];
    const float* knee   = (const float*)d_in[6];
    const float* makeup = (const float*)d_in[7];
    const float* mix    = (const float*)d_in[8];
    const float* bg     = (const float*)d_in[9];
    const float* bd     = (const float*)d_in[10];
    const float* noise  = (const float*)d_in[11];
    const float* fir    = (const float*)d_in[12];
    float* out = (float*)d_out;

    // ws: [flag 16B][acur2 33.55MB][smooth2 33.55MB][ir 8.39MB]; comp reuses acur2
    char*  w       = (char*)d_ws;
    int*   flag    = (int*)w;
    float* acur2   = (float*)(w + 16);
    float* smooth2 = acur2 + (size_t)NCHW * TLEN;
    float* ir      = smooth2 + (size_t)NCHW * TLEN;
    float* comp    = acur2;   // dead after k2

    k1_gain<<<TLEN / 64, 256, 0, stream>>>(x, drive, thr, ratio, knee, atk, bg, acur2, flag);
    k2_env<<<NCHUNK, 64, 0, stream>>>(acur2, atk, rel, smooth2);
    k3_out<<<TLEN / 64, 256, 0, stream>>>(x, smooth2, drive, makeup, mix, flag, out, comp);
    k4_ir<<<2048, 256, 0, stream>>>(noise, fir, bg, bd, flag, ir);
    k5_wet<<<2048, 256, 0, stream>>>(comp, ir, mix, flag, out);
}

// Round 4
// 255.070 us; speedup vs baseline: 1.3527x; 1.1207x over previous
//
#include <hip/hip_runtime.h>
#include <math.h>
#include <stdint.h>

// ---------------- problem constants ----------------
#define NCHW    64                 // BS*CHS = 32*2 channels (= wave width!)
#define TLEN    131072             // samples per channel
#define IRLEN   32768
#define NTAPS   511
#define NBANDS  12
#define NOISELEN (IRLEN + NTAPS - 1)   // 33278

// ---------------- scan chunking ----------------
#define WUP     4096
#define CHK     256
#define NCHUNK  (TLEN / CHK)       // 512

#define K10     0.16609640474436813f   // log2(10)/20
#define DB2     6.0205999132796239f    // 20*log10(2)

__device__ __forceinline__ float fast_tanh(float z) {
    float az = fabsf(z);
    float e  = exp2f(az * 2.8853900817779268f);
    float r  = 1.0f - 2.0f / (e + 1.0f);
    return copysignf(r, z);
}

__device__ __forceinline__ float gain_db_one(float xs, float g, float thr,
                                             float q, float knee, float inv2k) {
    float y    = fast_tanh(xs * g);
    float a    = fabsf(y) + 1e-8f;
    float xdb  = __log2f(a) * DB2;
    float over = xdb - thr;
    float h    = over + 0.5f * knee;
    float gk   = q * h * h * inv2k;
    float t2   = 2.0f * over;
    return (t2 < -knee) ? 0.0f : ((t2 > knee) ? q * over : gk);
}

// ---------- K1: gain computer -> transposed packed layout -----------------
// acur2 flat layout: addr(t, ch) = (t/2)*128 + ch*2 + (t&1)   [floats]
// stores ka = (1-alpha_a) * gain_db
__global__ __launch_bounds__(256) void k1_gain(
    const float* __restrict__ x,
    const float* __restrict__ p_drive, const float* __restrict__ p_thr,
    const float* __restrict__ p_ratio, const float* __restrict__ p_knee,
    const float* __restrict__ p_atk,   const float* __restrict__ band_gains,
    float* __restrict__ acur2, int* __restrict__ flag)
{
    if (blockIdx.x == 0 && threadIdx.x == 0) {
        int f = 0;
        #pragma unroll
        for (int b = 0; b < NBANDS; ++b) f |= (band_gains[b] != 0.0f) ? 1 : 0;
        *flag = f;
    }
    __shared__ float S[64 * 65];           // S[sample][ch], pitch 65
    int t0 = blockIdx.x * 64;
    int l  = threadIdx.x & 63;
    int w  = threadIdx.x >> 6;

    float g     = exp2f(p_drive[0] * K10);
    float thr   = p_thr[0];
    float knee  = fmaxf(p_knee[0], 1e-3f);
    float q     = 1.0f / p_ratio[0] - 1.0f;
    float inv2k = 1.0f / (2.0f * knee);
    float aa    = expf(-1.0f / (48.0f * p_atk[0]));
    float omaa  = 1.0f - aa;

    #pragma unroll
    for (int i = 0; i < 16; ++i) {
        int ch = w * 16 + i;
        float xv = x[(size_t)ch * TLEN + t0 + l];     // coalesced 256B/wave
        S[l * 65 + ch] = omaa * gain_db_one(xv, g, thr, q, knee, inv2k);
    }
    __syncthreads();

    float4* dst = (float4*)(acur2 + (size_t)t0 * 64);
    #pragma unroll
    for (int i = 0; i < 4; ++i) {
        int gq = threadIdx.x + 256 * i;
        int s2 = gq >> 5;
        int cp = (gq & 31) * 2;
        float4 v;
        v.x = S[(2 * s2)     * 65 + cp];
        v.y = S[(2 * s2 + 1) * 65 + cp];
        v.z = S[(2 * s2)     * 65 + cp + 1];
        v.w = S[(2 * s2 + 1) * 65 + cp + 1];
        dst[gq] = v;                      // coalesced 1KB/wave
    }
}

// ---------- K2: producer/consumer envelope scan ---------------------------
#define TI     32                  // float2-rows (2 samples) per tile
#define TILEF  (TI * 128)          // 4096 floats = 16 KB per tile

// wave-wide linear copy: 16 x (64 lanes x 16B) = 16 KB tile, global -> LDS DMA
__device__ __forceinline__ void stage_tile(const float* __restrict__ gsrc,
                                           float* lds_dst, int lane) {
    #pragma unroll
    for (int c = 0; c < 16; ++c) {
        __builtin_amdgcn_global_load_lds(
            (const __attribute__((address_space(1))) void*)(gsrc + c * 256 + lane * 4),
            (__attribute__((address_space(3))) void*)(lds_dst + c * 256),
            16, 0, 0);
    }
}

__global__ __launch_bounds__(128) void k2_env(
    const float* __restrict__ acur2,
    const float* __restrict__ p_atk, const float* __restrict__ p_rel,
    float* __restrict__ smooth2)
{
    __shared__ float lds[2 * TILEF];        // 32 KB double buffer
    int b    = blockIdx.x;
    int j    = ((b & 7) << 6) | (b >> 3);   // XCD-contiguous chunk ranges
    int lane = threadIdx.x & 63;            // channel
    int wv   = threadIdx.x >> 6;            // 0 = consumer, 1 = producer

    float aa  = expf(-1.0f / (48.0f * p_atk[0]));
    float ar  = expf(-1.0f / (48.0f * p_rel[0]));
    float rho = (1.0f - ar) / (1.0f - aa);

    int t0   = (j >= WUP / CHK) ? (j * CHK - WUP) : 0;   // exact for j<16
    int te   = j * CHK;
    int th0  = t0 >> 1, the = te >> 1, thend = (te + CHK) >> 1;
    int nt   = (thend - th0) / TI;          // trip count (integer by constr.)
    int ot   = (the - th0) / TI;            // first emitting tile

    const float* gbase = acur2 + (size_t)th0 * 128;
    float2* d2 = (float2*)smooth2 + lane;

    if (wv == 1) stage_tile(gbase, lds, lane);   // tile 0 -> buf 0

    float p = 0.0f;
    for (int tl = 0; tl < nt; ++tl) {
        __syncthreads();                    // tile tl resident (drains DMA)
        int buf = (tl & 1) ? TILEF : 0;
        if (wv == 1) {                      // producer: DMA tile tl+1 -> nbuf
            if (tl + 1 < nt)
                stage_tile(gbase + (size_t)(tl + 1) * TILEF,
                           lds + (TILEF - buf), lane);
        } else {                            // consumer: serial scan from LDS
            const float* L = lds + buf + lane * 2;
            int thb = th0 + tl * TI;
            if (tl >= ot) {
                #pragma unroll
                for (int u = 0; u < TI; ++u) {
                    float2 a = *(const float2*)(L + u * 128);
                    float fa = fmaf(aa, p, a.x);
                    float fr = fmaf(ar, p, rho * a.x);  // kr = rho*ka
                    p = fminf(fa, fr);                   // min = attack iff c<p
                    float2 o; o.x = p;
                    fa = fmaf(aa, p, a.y);
                    fr = fmaf(ar, p, rho * a.y);
                    p = fminf(fa, fr);
                    o.y = p;
                    d2[(size_t)(thb + u) * 64] = o;      // coalesced 512B/wave
                }
            } else {
                #pragma unroll
                for (int u = 0; u < TI; ++u) {
                    float2 a = *(const float2*)(L + u * 128);
                    float fa = fmaf(aa, p, a.x);
                    float fr = fmaf(ar, p, rho * a.x);
                    p = fminf(fa, fr);
                    fa = fmaf(aa, p, a.y);
                    fr = fmaf(ar, p, rho * a.y);
                    p = fminf(fa, fr);
                }
            }
        }
    }
}

// ---------- K3: transpose back + apply gain + dry mix ---------------------
__global__ __launch_bounds__(256) void k3_out(
    const float* __restrict__ x, const float* __restrict__ smooth2,
    const float* __restrict__ p_drive, const float* __restrict__ p_makeup,
    const float* __restrict__ p_mix, const int* __restrict__ flag,
    float* __restrict__ out, float* __restrict__ comp)
{
    __shared__ float S[32 * 130];
    __shared__ int sflag;
    if (threadIdx.x == 0) sflag = *flag;   // ONE flag load per block
    int t0 = blockIdx.x * 64;

    const float4* src = (const float4*)(smooth2 + (size_t)t0 * 64);
    #pragma unroll
    for (int i = 0; i < 4; ++i) {
        int f4 = threadIdx.x + 256 * i;
        float4 v = src[f4];                // coalesced 1KB/wave
        int f   = f4 * 4;
        float* d = S + (f >> 7) * 130 + (f & 127);
        d[0] = v.x; d[1] = v.y; d[2] = v.z; d[3] = v.w;
    }
    __syncthreads();

    int l = threadIdx.x & 63, w = threadIdx.x >> 6;
    float g   = exp2f(p_drive[0] * K10);
    float mk  = p_makeup[0];
    float mix = p_mix[0];
    float dry = 1.0f - mix;
    int f = sflag;

    #pragma unroll
    for (int i = 0; i < 16; ++i) {
        int ch = w * 16 + i;
        float sm = S[(l >> 1) * 130 + ch * 2 + (l & 1)];
        size_t idx = (size_t)ch * TLEN + t0 + l;
        float cv = fast_tanh(x[idx] * g) * exp2f((sm + mk) * K10);
        out[idx] = dry * cv;               // coalesced 256B/wave
        if (f) comp[idx] = cv;
    }
}

// ---------- K4 (guarded fallback): synthesize reverb IR -------------------
__global__ __launch_bounds__(256) void k4_ir(
    const float* __restrict__ noise, const float* __restrict__ fir,
    const float* __restrict__ gains, const float* __restrict__ decays,
    const int* __restrict__ flag, float* __restrict__ ir)
{
    __shared__ int sflag;
    if (threadIdx.x == 0) sflag = *flag;
    __syncthreads();
    if (!sflag) return;
    __shared__ float sf[NBANDS * NTAPS];
    for (int i = threadIdx.x; i < NBANDS * NTAPS; i += 256) sf[i] = fir[i];
    __syncthreads();
    size_t total  = (size_t)NCHW * IRLEN;
    size_t stride = (size_t)gridDim.x * 256;
    for (size_t idx = blockIdx.x * 256 + threadIdx.x; idx < total; idx += stride) {
        int nch = (int)(idx >> 15);
        int n   = (int)(idx & (IRLEN - 1));
        float tl  = n * (1.0f / (IRLEN - 1));
        float acc = 0.0f;
        for (int bb = 0; bb < NBANDS; ++bb) {
            float gb = gains[bb];
            if (gb == 0.0f) continue;
            float env = expf(-(decays[bb] * 10.0f + 1.0f) * tl) * gb;
            const float* np_ = noise + ((size_t)nch * NBANDS + bb) * NOISELEN + n;
            const float* fb  = sf + bb * NTAPS;
            float s = 0.0f;
            for (int k = 0; k < NTAPS; ++k) s = fmaf(np_[k], fb[k], s);
            acc = fmaf(env, s, acc);
        }
        ir[idx] = acc * (1.0f / NBANDS);
    }
}

// ---------- K5 (guarded fallback): wet convolution + mix ------------------
__global__ __launch_bounds__(256) void k5_wet(
    const float* __restrict__ comp, const float* __restrict__ ir,
    const float* __restrict__ p_mix, const int* __restrict__ flag,
    float* __restrict__ out)
{
    __shared__ int sflag;
    if (threadIdx.x == 0) sflag = *flag;
    __syncthreads();
    if (!sflag) return;
    float mix = p_mix[0];
    size_t total  = (size_t)NCHW * TLEN;
    size_t stride = (size_t)gridDim.x * 256;
    for (size_t idx = blockIdx.x * 256 + threadIdx.x; idx < total; idx += stride) {
        int nch = (int)(idx >> 17);
        int t   = (int)(idx & (TLEN - 1));
        const float* c   = comp + (size_t)nch * TLEN;
        const float* irp = ir + (size_t)nch * IRLEN;
        int kmax = (t < IRLEN - 1) ? t : (IRLEN - 1);
        float s = 0.0f;
        for (int k = 0; k <= kmax; ++k) s = fmaf(irp[k], c[t - k], s);
        out[idx] += mix * s;
    }
}

// ---------- host-side launch ----------------------------------------------
extern "C" void kernel_launch(void* const* d_in, const int* in_sizes, int n_in,
                              void* d_out, int out_size, void* d_ws, size_t ws_size,
                              hipStream_t stream)
{
    const float* x      = (const float*)d_in[0];
    const float* drive  = (const float*)d_in[1];
    const float* thr    = (const float*)d_in[2];
    const float* ratio  = (const float*)d_in[3];
    const float* atk    = (const float*)d_in[4];
    const float* rel    = (const float*)d_in[5];
    const float* knee   = (const float*)d_in[6];
    const float* makeup = (const float*)d_in[7];
    const float* mix    = (const float*)d_in[8];
    const float* bg     = (const float*)d_in[9];
    const float* bd     = (const float*)d_in[10];
    const float* noise  = (const float*)d_in[11];
    const float* fir    = (const float*)d_in[12];
    float* out = (float*)d_out;

    // ws: [flag 16B][acur2 33.55MB][smooth2 33.55MB][ir 8.39MB]; comp reuses acur2
    char*  w       = (char*)d_ws;
    int*   flag    = (int*)w;
    float* acur2   = (float*)(w + 16);
    float* smooth2 = acur2 + (size_t)NCHW * TLEN;
    float* ir      = smooth2 + (size_t)NCHW * TLEN;
    float* comp    = acur2;   // dead after k2

    k1_gain<<<TLEN / 64, 256, 0, stream>>>(x, drive, thr, ratio, knee, atk, bg, acur2, flag);
    k2_env<<<NCHUNK, 128, 0, stream>>>(acur2, atk, rel, smooth2);
    k3_out<<<TLEN / 64, 256, 0, stream>>>(x, smooth2, drive, makeup, mix, flag, out, comp);
    k4_ir<<<1024, 256, 0, stream>>>(noise, fir, bg, bd, flag, ir);
    k5_wet<<<1024, 256, 0, stream>>>(comp, ir, mix, flag, out);
}

// Round 5
// 254.246 us; speedup vs baseline: 1.3571x; 1.0032x over previous
//
#include <hip/hip_runtime.h>
#include <math.h>
#include <stdint.h>

// ---------------- problem constants ----------------
#define NCHW    64                 // BS*CHS = 32*2 channels (= wave width!)
#define TLEN    131072             // samples per channel
#define IRLEN   32768
#define NTAPS   511
#define NBANDS  12
#define NOISELEN (IRLEN + NTAPS - 1)   // 33278

// ---------------- scan chunking ----------------
#define WUP     4096
#define CHK     256
#define NCHUNK  (TLEN / CHK)       // 512

#define K10     0.16609640474436813f   // log2(10)/20
#define DB2     6.0205999132796239f    // 20*log10(2)

__device__ __forceinline__ float fast_tanh(float z) {
    float az = fabsf(z);
    float e  = exp2f(az * 2.8853900817779268f);
    float r  = 1.0f - 2.0f / (e + 1.0f);
    return copysignf(r, z);
}

__device__ __forceinline__ float gain_db_one(float xs, float g, float thr,
                                             float q, float knee, float inv2k) {
    float y    = fast_tanh(xs * g);
    float a    = fabsf(y) + 1e-8f;
    float xdb  = __log2f(a) * DB2;
    float over = xdb - thr;
    float h    = over + 0.5f * knee;
    float gk   = q * h * h * inv2k;
    float t2   = 2.0f * over;
    return (t2 < -knee) ? 0.0f : ((t2 > knee) ? q * over : gk);
}

// ---------- K1: gain computer -> transposed packed layout -----------------
// acur2 flat layout: addr(t, ch) = (t/2)*128 + ch*2 + (t&1)   [floats]
// stores ka = (1-alpha_a) * gain_db
__global__ __launch_bounds__(256) void k1_gain(
    const float* __restrict__ x,
    const float* __restrict__ p_drive, const float* __restrict__ p_thr,
    const float* __restrict__ p_ratio, const float* __restrict__ p_knee,
    const float* __restrict__ p_atk,   const float* __restrict__ band_gains,
    float* __restrict__ acur2, int* __restrict__ flag)
{
    if (blockIdx.x == 0 && threadIdx.x == 0) {
        int f = 0;
        #pragma unroll
        for (int b = 0; b < NBANDS; ++b) f |= (band_gains[b] != 0.0f) ? 1 : 0;
        *flag = f;
    }
    __shared__ float S[64 * 65];           // S[sample][ch], pitch 65
    int t0 = blockIdx.x * 64;
    int l  = threadIdx.x & 63;
    int w  = threadIdx.x >> 6;

    float g     = exp2f(p_drive[0] * K10);
    float thr   = p_thr[0];
    float knee  = fmaxf(p_knee[0], 1e-3f);
    float q     = 1.0f / p_ratio[0] - 1.0f;
    float inv2k = 1.0f / (2.0f * knee);
    float aa    = expf(-1.0f / (48.0f * p_atk[0]));
    float omaa  = 1.0f - aa;

    #pragma unroll
    for (int i = 0; i < 16; ++i) {
        int ch = w * 16 + i;
        float xv = x[(size_t)ch * TLEN + t0 + l];     // coalesced 256B/wave
        S[l * 65 + ch] = omaa * gain_db_one(xv, g, thr, q, knee, inv2k);
    }
    __syncthreads();

    float4* dst = (float4*)(acur2 + (size_t)t0 * 64);
    #pragma unroll
    for (int i = 0; i < 4; ++i) {
        int gq = threadIdx.x + 256 * i;
        int s2 = gq >> 5;
        int cp = (gq & 31) * 2;
        float4 v;
        v.x = S[(2 * s2)     * 65 + cp];
        v.y = S[(2 * s2 + 1) * 65 + cp];
        v.z = S[(2 * s2)     * 65 + cp + 1];
        v.w = S[(2 * s2 + 1) * 65 + cp + 1];
        dst[gq] = v;                      // coalesced 1KB/wave
    }
}

// ---------- K2: producer/consumer envelope scan ---------------------------
#define ROWS   64                  // float2-rows (2 samples) per tile
#define TILEF  (ROWS * 128)        // 8192 floats = 32 KB per tile

// wave-wide linear copy: 32 x (64 lanes x 16B) = 32 KB tile, global -> LDS DMA
__device__ __forceinline__ void stage_tile(const float* __restrict__ gsrc,
                                           float* lds_dst, int lane) {
    #pragma unroll
    for (int c = 0; c < 32; ++c) {
        __builtin_amdgcn_global_load_lds(
            (const __attribute__((address_space(1))) void*)(gsrc + c * 256 + lane * 4),
            (__attribute__((address_space(3))) void*)(lds_dst + c * 256),
            16, 0, 0);
    }
}

__global__ __launch_bounds__(128) void k2_env(
    const float* __restrict__ acur2,
    const float* __restrict__ p_atk, const float* __restrict__ p_rel,
    float* __restrict__ smooth2)
{
    __shared__ float lds[2 * TILEF];        // 64 KB double buffer
    int b    = blockIdx.x;
    int j    = ((b & 7) << 6) | (b >> 3);   // XCD-contiguous chunk ranges
    int lane = threadIdx.x & 63;            // channel
    int wv   = threadIdx.x >> 6;            // 0 = consumer, 1 = producer

    float aa  = expf(-1.0f / (48.0f * p_atk[0]));
    float ar  = expf(-1.0f / (48.0f * p_rel[0]));
    float rho = (1.0f - ar) / (1.0f - aa);

    int t0   = (j >= WUP / CHK) ? (j * CHK - WUP) : 0;   // exact for j<16
    int te   = j * CHK;
    int th0  = t0 >> 1, the = te >> 1, thend = (te + CHK) >> 1;
    int nt   = (thend - th0) / ROWS;        // trip count (integer by constr.)
    int ot   = (the - th0) / ROWS;          // first emitting tile

    const float* gbase = acur2 + (size_t)th0 * 128;
    float2* d2 = (float2*)smooth2 + lane;

    if (wv == 1) stage_tile(gbase, lds, lane);   // tile 0 -> buf 0

    float p = 0.0f;
    for (int tl = 0; tl < nt; ++tl) {
        __syncthreads();                    // tile tl resident (drains DMA)
        int buf = (tl & 1) ? TILEF : 0;
        if (wv == 1) {                      // producer: DMA tile tl+1 -> nbuf
            if (tl + 1 < nt)
                stage_tile(gbase + (size_t)(tl + 1) * TILEF,
                           lds + (TILEF - buf), lane);
        } else {                            // consumer: serial scan from LDS
            const float* L = lds + buf + lane * 2;
            int thb = th0 + tl * ROWS;
            if (tl >= ot) {
                #pragma unroll
                for (int u = 0; u < ROWS; ++u) {
                    float2 a = *(const float2*)(L + u * 128);
                    float fa = fmaf(aa, p, a.x);
                    float fr = fmaf(ar, p, rho * a.x);  // kr = rho*ka
                    p = fminf(fa, fr);                   // min = attack iff c<p
                    float2 o; o.x = p;
                    fa = fmaf(aa, p, a.y);
                    fr = fmaf(ar, p, rho * a.y);
                    p = fminf(fa, fr);
                    o.y = p;
                    d2[(size_t)(thb + u) * 64] = o;      // coalesced 512B/wave
                }
            } else {
                #pragma unroll
                for (int u = 0; u < ROWS; ++u) {
                    float2 a = *(const float2*)(L + u * 128);
                    float fa = fmaf(aa, p, a.x);
                    float fr = fmaf(ar, p, rho * a.x);
                    p = fminf(fa, fr);
                    fa = fmaf(aa, p, a.y);
                    fr = fmaf(ar, p, rho * a.y);
                    p = fminf(fa, fr);
                }
            }
        }
    }
}

// ---------- K3: transpose back + apply gain + dry mix ---------------------
__global__ __launch_bounds__(256) void k3_out(
    const float* __restrict__ x, const float* __restrict__ smooth2,
    const float* __restrict__ p_drive, const float* __restrict__ p_makeup,
    const float* __restrict__ p_mix, const int* __restrict__ flag,
    float* __restrict__ out, float* __restrict__ comp)
{
    __shared__ float S[32 * 130];
    __shared__ int sflag;
    if (threadIdx.x == 0) sflag = *flag;   // ONE flag load per block
    int t0 = blockIdx.x * 64;

    const float4* src = (const float4*)(smooth2 + (size_t)t0 * 64);
    #pragma unroll
    for (int i = 0; i < 4; ++i) {
        int f4 = threadIdx.x + 256 * i;
        float4 v = src[f4];                // coalesced 1KB/wave
        int f   = f4 * 4;
        float* d = S + (f >> 7) * 130 + (f & 127);
        d[0] = v.x; d[1] = v.y; d[2] = v.z; d[3] = v.w;
    }
    __syncthreads();

    int l = threadIdx.x & 63, w = threadIdx.x >> 6;
    float g   = exp2f(p_drive[0] * K10);
    float mk  = p_makeup[0];
    float mix = p_mix[0];
    float dry = 1.0f - mix;
    int f = sflag;

    #pragma unroll
    for (int i = 0; i < 16; ++i) {
        int ch = w * 16 + i;
        float sm = S[(l >> 1) * 130 + ch * 2 + (l & 1)];
        size_t idx = (size_t)ch * TLEN + t0 + l;
        float cv = fast_tanh(x[idx] * g) * exp2f((sm + mk) * K10);
        out[idx] = dry * cv;               // coalesced 256B/wave
        if (f) comp[idx] = cv;
    }
}

// ---------- K4 (guarded fallback): synthesize reverb IR -------------------
__global__ __launch_bounds__(256) void k4_ir(
    const float* __restrict__ noise, const float* __restrict__ fir,
    const float* __restrict__ gains, const float* __restrict__ decays,
    const int* __restrict__ flag, float* __restrict__ ir)
{
    __shared__ int sflag;
    if (threadIdx.x == 0) sflag = *flag;
    __syncthreads();
    if (!sflag) return;
    __shared__ float sf[NBANDS * NTAPS];
    for (int i = threadIdx.x; i < NBANDS * NTAPS; i += 256) sf[i] = fir[i];
    __syncthreads();
    size_t total  = (size_t)NCHW * IRLEN;
    size_t stride = (size_t)gridDim.x * 256;
    for (size_t idx = blockIdx.x * 256 + threadIdx.x; idx < total; idx += stride) {
        int nch = (int)(idx >> 15);
        int n   = (int)(idx & (IRLEN - 1));
        float tl  = n * (1.0f / (IRLEN - 1));
        float acc = 0.0f;
        for (int bb = 0; bb < NBANDS; ++bb) {
            float gb = gains[bb];
            if (gb == 0.0f) continue;
            float env = expf(-(decays[bb] * 10.0f + 1.0f) * tl) * gb;
            const float* np_ = noise + ((size_t)nch * NBANDS + bb) * NOISELEN + n;
            const float* fb  = sf + bb * NTAPS;
            float s = 0.0f;
            for (int k = 0; k < NTAPS; ++k) s = fmaf(np_[k], fb[k], s);
            acc = fmaf(env, s, acc);
        }
        ir[idx] = acc * (1.0f / NBANDS);
    }
}

// ---------- K5 (guarded fallback): wet convolution + mix ------------------
__global__ __launch_bounds__(256) void k5_wet(
    const float* __restrict__ comp, const float* __restrict__ ir,
    const float* __restrict__ p_mix, const int* __restrict__ flag,
    float* __restrict__ out)
{
    __shared__ int sflag;
    if (threadIdx.x == 0) sflag = *flag;
    __syncthreads();
    if (!sflag) return;
    float mix = p_mix[0];
    size_t total  = (size_t)NCHW * TLEN;
    size_t stride = (size_t)gridDim.x * 256;
    for (size_t idx = blockIdx.x * 256 + threadIdx.x; idx < total; idx += stride) {
        int nch = (int)(idx >> 17);
        int t   = (int)(idx & (TLEN - 1));
        const float* c   = comp + (size_t)nch * TLEN;
        const float* irp = ir + (size_t)nch * IRLEN;
        int kmax = (t < IRLEN - 1) ? t : (IRLEN - 1);
        float s = 0.0f;
        for (int k = 0; k <= kmax; ++k) s = fmaf(irp[k], c[t - k], s);
        out[idx] += mix * s;
    }
}

// ---------- host-side launch ----------------------------------------------
extern "C" void kernel_launch(void* const* d_in, const int* in_sizes, int n_in,
                              void* d_out, int out_size, void* d_ws, size_t ws_size,
                              hipStream_t stream)
{
    const float* x      = (const float*)d_in[0];
    const float* drive  = (const float*)d_in[1];
    const float* thr    = (const float*)d_in[2];
    const float* ratio  = (const float*)d_in[3];
    const float* atk    = (const float*)d_in[4];
    const float* rel    = (const float*)d_in[5];
    const float* knee   = (const float*)d_in[6];
    const float* makeup = (const float*)d_in[7];
    const float* mix    = (const float*)d_in[8];
    const float* bg     = (const float*)d_in[9];
    const float* bd     = (const float*)d_in[10];
    const float* noise  = (const float*)d_in[11];
    const float* fir    = (const float*)d_in[12];
    float* out = (float*)d_out;

    // ws: [flag 16B][acur2 33.55MB][smooth2 33.55MB][ir 8.39MB]; comp reuses acur2
    char*  w       = (char*)d_ws;
    int*   flag    = (int*)w;
    float* acur2   = (float*)(w + 16);
    float* smooth2 = acur2 + (size_t)NCHW * TLEN;
    float* ir      = smooth2 + (size_t)NCHW * TLEN;
    float* comp    = acur2;   // dead after k2

    k1_gain<<<TLEN / 64, 256, 0, stream>>>(x, drive, thr, ratio, knee, atk, bg, acur2, flag);
    k2_env<<<NCHUNK, 128, 0, stream>>>(acur2, atk, rel, smooth2);
    k3_out<<<TLEN / 64, 256, 0, stream>>>(x, smooth2, drive, makeup, mix, flag, out, comp);
    k4_ir<<<1024, 256, 0, stream>>>(noise, fir, bg, bd, flag, ir);
    k5_wet<<<1024, 256, 0, stream>>>(comp, ir, mix, flag, out);
}